// Round 1
// 668.317 us; speedup vs baseline: 1.4791x; 1.4791x over previous
//
#include <hip/hip_runtime.h>
#include <hip/hip_bf16.h>
#include <stdint.h>

// JointAttention: B=1, L=512(txt), N=4096(img), HID=1536, H=12, D=128
// Round 3: inputs are fp32 (98MB npz == fp32 footprint). Convert all GEMM
// operands to bf16 ONCE (convert6), so gemm_core staging is pure bf16
// (1x 16B load per fragment, no per-tile cvt VALU). Merge txt+img qkv into
// one 36x36 dispatch and txt+img out-proj into one 12x36 dispatch (fixes
// 144/48-block underfill). attn unchanged this round.
// ws (u16 elems): qb[0) kb[7077888) vb[14155776) ob[21233664)
//   txtb[28311552) imgb[29097984) Wqtb[35389440) Wqib[42467328)
//   Wotb[49545216) Woib[51904512) end 54263808 -> 108.5 MB.
// If ws_size < 108.5 MB: fall back to runtime-dtype staging (baseline path).

typedef __attribute__((ext_vector_type(8))) short short8;
typedef __attribute__((ext_vector_type(4))) float floatx4;

#define DEV __device__ __forceinline__

DEV float bf2f(uint16_t s) {
  union { uint32_t u; float f; } v;
  v.u = (uint32_t)s << 16;
  return v.f;
}
DEV uint16_t f2bf(float f) {
  __hip_bfloat16 h = __float2bfloat16(f);
  return __builtin_bit_cast(uint16_t, h);
}

// Distinguish bf16 vs fp32 buffers: for bf16 N(0,sigma) data, even-indexed
// u16s are bf16 samples (sane exponents). For fp32 data, even u16s are low
// mantissa bits (~21% "sane"). Majority vote over 64.
DEV bool detect_bf16(const void* p) {
  const uint16_t* u = (const uint16_t*)p;
  int sane = 0;
  for (int i = 0; i < 64; ++i) {
    int e = (u[2 * i] >> 7) & 0xFF;
    sane += (e > 90 && e < 145) ? 1 : 0;
  }
  return sane >= 40;
}

DEV short8 load8(const void* base, long idx, bool bf) {
  if (bf) return *(const short8*)((const uint16_t*)base + idx);
  const floatx4* f = (const floatx4*)((const float*)base + idx);
  floatx4 a = f[0], b = f[1];
  short8 r;
  r[0] = (short)f2bf(a[0]); r[1] = (short)f2bf(a[1]);
  r[2] = (short)f2bf(a[2]); r[3] = (short)f2bf(a[3]);
  r[4] = (short)f2bf(b[0]); r[5] = (short)f2bf(b[1]);
  r[6] = (short)f2bf(b[2]); r[7] = (short)f2bf(b[3]);
  return r;
}

DEV float loadElem(const void* base, long idx, bool bf) {
  return bf ? bf2f(((const uint16_t*)base)[idx]) : ((const float*)base)[idx];
}

// ---------------------------------------------------------------------------
// One-time fp32->bf16 (or bf16 copy) of the 6 GEMM operand tensors into ws.
__global__ void convert6(const void* s0, const void* s1, const void* s2,
                         const void* s3, const void* s4, const void* s5,
                         uint16_t* ws) {
  const void* s;
  uint16_t* d;
  long n;
  switch (blockIdx.y) {
    case 0: s = s0; d = ws + 28311552L; n = 786432L; break;   // txt
    case 1: s = s1; d = ws + 29097984L; n = 6291456L; break;  // img
    case 2: s = s2; d = ws + 35389440L; n = 7077888L; break;  // W_txt_qkv
    case 3: s = s3; d = ws + 42467328L; n = 7077888L; break;  // W_img_qkv
    case 4: s = s4; d = ws + 49545216L; n = 2359296L; break;  // W_txt_out
    default: s = s5; d = ws + 51904512L; n = 2359296L; break; // W_img_out
  }
  const bool bf = detect_bf16(s);
  const long stride = (long)gridDim.x * blockDim.x * 8;
  for (long i = ((long)blockIdx.x * blockDim.x + threadIdx.x) * 8; i < n;
       i += stride) {
    if (bf) {
      *(short8*)(d + i) = *(const short8*)((const uint16_t*)s + i);
    } else {
      const floatx4* f = (const floatx4*)((const float*)s + i);
      floatx4 a = f[0], b = f[1];
      short8 r;
      r[0] = (short)f2bf(a[0]); r[1] = (short)f2bf(a[1]);
      r[2] = (short)f2bf(a[2]); r[3] = (short)f2bf(a[3]);
      r[4] = (short)f2bf(b[0]); r[5] = (short)f2bf(b[1]);
      r[6] = (short)f2bf(b[2]); r[7] = (short)f2bf(b[3]);
      *(short8*)(d + i) = r;
    }
  }
}

// ---------------------------------------------------------------------------
// acc[4][4] for C tile (bm,bn) of A[M,K] * B[N,K]^T via bf16 MFMA.
// 128x128 tile, BK=32, register staging + ds_write_b128, XOR chunk swizzle:
// (row, chunk g) lives at slot g^(row&3) so frag ds_read_b128 is low-conflict.
DEV void gemm_core(const void* A, const void* B, bool abf, bool bbf, long bm,
                   long bn, int K, uint16_t* sA, uint16_t* sB,
                   floatx4 (&acc)[4][4]) {
  const int t = threadIdx.x;
  const int lane = t & 63, wave = t >> 6, l16 = lane & 15, quad = lane >> 4;
  const int srow = t >> 2, c = t & 3, g = c ^ (srow & 3);
  const int wm = (wave >> 1) * 64, wn = (wave & 1) * 64;
  const int fsl = (quad ^ (l16 & 3)) * 8;
  for (int k0 = 0; k0 < K; k0 += 32) {
    short8 a0 = load8(A, (bm + srow) * (long)K + k0 + g * 8, abf);
    short8 a1 = load8(A, (bm + 64 + srow) * (long)K + k0 + g * 8, abf);
    short8 b0 = load8(B, (bn + srow) * (long)K + k0 + g * 8, bbf);
    short8 b1 = load8(B, (bn + 64 + srow) * (long)K + k0 + g * 8, bbf);
    __syncthreads();  // prev-iter frag reads done before overwrite
    *(short8*)(sA + srow * 32 + c * 8) = a0;
    *(short8*)(sA + (64 + srow) * 32 + c * 8) = a1;
    *(short8*)(sB + srow * 32 + c * 8) = b0;
    *(short8*)(sB + (64 + srow) * 32 + c * 8) = b1;
    __syncthreads();
    short8 af[4], bfr[4];
#pragma unroll
    for (int i = 0; i < 4; ++i) {
      af[i] = *(const short8*)(sA + (wm + i * 16 + l16) * 32 + fsl);
      bfr[i] = *(const short8*)(sB + (wn + i * 16 + l16) * 32 + fsl);
    }
#pragma unroll
    for (int i = 0; i < 4; ++i)
#pragma unroll
      for (int j = 0; j < 4; ++j)
        acc[i][j] = __builtin_amdgcn_mfma_f32_16x16x32_bf16(af[i], bfr[j],
                                                            acc[i][j], 0, 0, 0);
  }
}

// ---------------------------------------------------------------------------
// Merged QKV gemm (txt rows 0..511 from Atxt*Btxt, img rows 512.. from
// Aimg*Bimg) with fused scatter + rope. Column tile = one (tensor tt, head h):
// th = blockIdx.x, tt = th/12, h = th%12. Rope (img q,k only): d and d^1 are
// in adjacent lanes -> __shfl_xor(v,1).
__global__ __launch_bounds__(256, 2) void qkv_gemm(
    const void* Atxt, const void* Aimg, const void* Btxt, const void* Bimg,
    const void* rope, const void* det, int conv, uint16_t* qb, uint16_t* kb,
    uint16_t* vb) {
  __shared__ uint16_t sA[128 * 32], sB[128 * 32];
  const bool dbf = detect_bf16(det);      // original input dtype (rope)
  const bool bf = conv ? true : dbf;      // A/B operand dtype
  const int bmb = blockIdx.y;
  const long g0 = (long)bmb * 128;        // global seq row of this block
  const bool is_img = bmb >= 4;           // 4*128 == 512 txt rows
  const void* A = is_img ? Aimg : Atxt;
  const void* B = is_img ? Bimg : Btxt;
  const long bmA = is_img ? g0 - 512 : g0;
  const long bn = (long)blockIdx.x * 128;
  floatx4 acc[4][4] = {};
  gemm_core(A, B, bf, bf, bmA, bn, 1536, sA, sB, acc);

  const int t = threadIdx.x, lane = t & 63, wave = t >> 6;
  const int l16 = lane & 15, quad = lane >> 4;
  const int wm = (wave >> 1) * 64, wn = (wave & 1) * 64;
  const int th = blockIdx.x;
  const int tt = th / 12, h = th - tt * 12;
  uint16_t* dst = tt == 0 ? qb : (tt == 1 ? kb : vb);
  const bool do_rope = is_img && (tt < 2);
#pragma unroll
  for (int i = 0; i < 4; ++i)
#pragma unroll
    for (int j = 0; j < 4; ++j)
#pragma unroll
      for (int r = 0; r < 4; ++r) {
        long g = g0 + wm + i * 16 + quad * 4 + r;  // global seq row
        int d = wn + j * 16 + l16;
        float v = acc[i][j][r];
        float p = __shfl_xor(v, 1);  // partner element of the rope pair
        if (do_rope) {
          int dp = d & ~1;
          long ri = (g - 512) * 128 + dp;
          float cc = loadElem(rope, ri, dbf);
          float ss = loadElem(rope, ri + 1, dbf);
          v = (d & 1) ? (v * cc + p * ss) : (v * cc - p * ss);
        }
        dst[((long)h * 4608 + g) * 128 + d] = f2bf(v);
      }
}

// ---------------------------------------------------------------------------
// Merged out-projection gemm: A = attention output (ws, bf16); B = W_txt_out
// for rows<512 else W_img_out; C = d_out in detected original dtype.
__global__ __launch_bounds__(256, 2) void out_gemm(
    const uint16_t* Abf, const void* Btxt, const void* Bimg, const void* det,
    int conv, void* out) {
  __shared__ uint16_t sA[128 * 32], sB[128 * 32];
  const bool dbf = detect_bf16(det);
  const bool bbf = conv ? true : dbf;
  const int bmb = blockIdx.y;
  const long bm = (long)bmb * 128;
  const void* B = bmb >= 4 ? Bimg : Btxt;
  const long bn = (long)blockIdx.x * 128;
  floatx4 acc[4][4] = {};
  gemm_core(Abf, B, true, bbf, bm, bn, 1536, sA, sB, acc);

  const int t = threadIdx.x, lane = t & 63, wave = t >> 6;
  const int l16 = lane & 15, quad = lane >> 4;
  const int wm = (wave >> 1) * 64, wn = (wave & 1) * 64;
#pragma unroll
  for (int i = 0; i < 4; ++i)
#pragma unroll
    for (int j = 0; j < 4; ++j)
#pragma unroll
      for (int r = 0; r < 4; ++r) {
        long row = bm + wm + i * 16 + quad * 4 + r;
        long col = bn + wn + j * 16 + l16;
        long idx = row * 1536 + col;
        if (dbf) ((uint16_t*)out)[idx] = f2bf(acc[i][j][r]);
        else ((float*)out)[idx] = acc[i][j][r];
      }
}

// ---------------------------------------------------------------------------
// Flash attention. Block = (64 q-rows, head); 4 waves x 16 q-rows.
// Per 32-key tile: K staged row-major (chunk slot g^(row&15)); V staged
// transposed sVt[d][key] (chunk-swizzled); P C->A transpose via per-wave
// LDS stash; row-sum via MFMA against all-ones B; row-max via shfl_xor.
__global__ __launch_bounds__(256, 2) void attn(
    const uint16_t* __restrict__ qb, const uint16_t* __restrict__ kb,
    const uint16_t* __restrict__ vb, uint16_t* __restrict__ ob) {
  __shared__ uint16_t sK[32 * 128];
  __shared__ uint16_t sVt[128 * 32];
  __shared__ uint16_t sP[4][16 * 32];

  const int t = threadIdx.x;
  const int lane = t & 63, wave = t >> 6;
  const int l16 = lane & 15, quad = lane >> 4;
  const int h = blockIdx.y;
  const int q0 = blockIdx.x * 64 + wave * 16;

  const uint16_t* Qh = qb + (long)h * 4608 * 128;
  const uint16_t* Kh = kb + (long)h * 4608 * 128;
  const uint16_t* Vh = vb + (long)h * 4608 * 128;

  short8 aq[4];
#pragma unroll
  for (int dk = 0; dk < 4; ++dk)
    aq[dk] = *(const short8*)(Qh + (long)(q0 + l16) * 128 + dk * 32 + quad * 8);

  short8 ones;
#pragma unroll
  for (int j = 0; j < 8; ++j) ones[j] = (short)0x3F80;  // bf16 1.0

  float m_i[4] = {-1e30f, -1e30f, -1e30f, -1e30f};
  floatx4 accL = {};
  floatx4 accO[8] = {};

  // K staging: 8 threads/row, 2 chunks (16B) each; slot = chunk ^ (row&15)
  const int krow = t >> 3;       // 0..31
  const int kc2 = (t & 7) * 2;   // even chunk index (of 16 per row)
  const int ks0 = (kc2 ^ (krow & 15)) * 8;
  const int ks1 = ((kc2 + 1) ^ (krow & 15)) * 8;
  // V staging: key pair x 8 d per thread
  const int vkp = (t & 15) * 2;
  const int vdb = (t >> 4) * 8;

  uint16_t* pw = &sP[wave][0];
  const int pf_off = l16 * 64 + ((quad ^ ((l16 ^ (l16 >> 2)) & 3)) * 16);

  for (int kt = 0; kt < 144; ++kt) {
    const int key0 = kt * 32;
    short8 kv0 = *(const short8*)(Kh + (long)(key0 + krow) * 128 + kc2 * 8);
    short8 kv1 = *(const short8*)(Kh + (long)(key0 + krow) * 128 + kc2 * 8 + 8);
    short8 va = *(const short8*)(Vh + (long)(key0 + vkp) * 128 + vdb);
    short8 vn = *(const short8*)(Vh + (long)(key0 + vkp + 1) * 128 + vdb);
    __syncthreads();  // prev-iter LDS reads complete
    *(short8*)(sK + krow * 128 + ks0) = kv0;
    *(short8*)(sK + krow * 128 + ks1) = kv1;
#pragma unroll
    for (int j = 0; j < 8; ++j) {
      int d = vdb + j;
      int ch = (vkp >> 3) ^ ((d ^ (d >> 2)) & 3);
      uint32_t pack = (uint16_t)va[j] | ((uint32_t)(uint16_t)vn[j] << 16);
      *(uint32_t*)((char*)sVt + d * 64 + ch * 16 + (vkp & 7) * 2) = pack;
    }
    __syncthreads();

    // S = Q K^T
    floatx4 sc[2] = {};
#pragma unroll
    for (int ns = 0; ns < 2; ++ns) {
      const int row = ns * 16 + l16;
#pragma unroll
      for (int dk = 0; dk < 4; ++dk) {
        short8 bk =
            *(const short8*)(sK + row * 128 + (((dk * 4 + quad) ^ l16) * 8));
        sc[ns] = __builtin_amdgcn_mfma_f32_16x16x32_bf16(aq[dk], bk, sc[ns],
                                                         0, 0, 0);
      }
    }

    // online softmax
    float alpha[4];
#pragma unroll
    for (int r = 0; r < 4; ++r) {
      float s0 = sc[0][r] * 0.08838834764831845f;
      float s1 = sc[1][r] * 0.08838834764831845f;
      float mx = fmaxf(s0, s1);
      mx = fmaxf(mx, __shfl_xor(mx, 1));
      mx = fmaxf(mx, __shfl_xor(mx, 2));
      mx = fmaxf(mx, __shfl_xor(mx, 4));
      mx = fmaxf(mx, __shfl_xor(mx, 8));
      float mn = fmaxf(m_i[r], mx);
      alpha[r] = __expf(m_i[r] - mn);
      m_i[r] = mn;
      sc[0][r] = __expf(s0 - mn);
      sc[1][r] = __expf(s1 - mn);
    }

    // P -> per-wave stash (C->A transpose), chunk-swizzled
#pragma unroll
    for (int ns = 0; ns < 2; ++ns)
#pragma unroll
      for (int r = 0; r < 4; ++r) {
        const int row = quad * 4 + r;
        const int col = ns * 16 + l16;
        const int ch = (col >> 3) ^ ((row ^ (row >> 2)) & 3);
        *(uint16_t*)((char*)pw + row * 64 + ch * 16 + (col & 7) * 2) =
            f2bf(sc[ns][r]);
      }
    asm volatile("s_waitcnt lgkmcnt(0)" ::: "memory");  // same-wave stash drain

#pragma unroll
    for (int vt = 0; vt < 8; ++vt)
#pragma unroll
      for (int r = 0; r < 4; ++r) accO[vt][r] *= alpha[r];
#pragma unroll
    for (int r = 0; r < 4; ++r) accL[r] *= alpha[r];

    short8 pf = *(const short8*)((char*)pw + pf_off);
    accL = __builtin_amdgcn_mfma_f32_16x16x32_bf16(pf, ones, accL, 0, 0, 0);
#pragma unroll
    for (int vt = 0; vt < 8; ++vt) {
      const int d = vt * 16 + l16;
      short8 bv = *(const short8*)((char*)sVt + d * 64 +
                                   ((quad ^ ((d ^ (d >> 2)) & 3)) * 16));
      accO[vt] = __builtin_amdgcn_mfma_f32_16x16x32_bf16(pf, bv, accO[vt],
                                                         0, 0, 0);
    }
  }

#pragma unroll
  for (int r = 0; r < 4; ++r) {
    const long row = q0 + quad * 4 + r;
    const float inv = 1.f / accL[r];
#pragma unroll
    for (int vt = 0; vt < 8; ++vt)
      ob[row * 1536 + h * 128 + vt * 16 + l16] =
          f2bf(accO[vt][r] * inv);
  }
}

// ---------------------------------------------------------------------------
extern "C" void kernel_launch(void* const* d_in, const int* in_sizes, int n_in,
                              void* d_out, int out_size, void* d_ws,
                              size_t ws_size, hipStream_t stream) {
  const void* txt = d_in[0];
  const void* img = d_in[1];
  const void* rope = d_in[2];
  const void* Wtq = d_in[3];
  const void* Wiq = d_in[4];
  const void* Wto = d_in[5];
  const void* Wio = d_in[6];

  uint16_t* ws = (uint16_t*)d_ws;
  uint16_t* qb = ws;                  // [12][4608][128]
  uint16_t* kb = ws + 7077888L;
  uint16_t* vb = ws + 14155776L;
  uint16_t* ob = ws + 21233664L;      // [4608][1536]

  const size_t NEED = 108527616ULL;   // 54,263,808 u16 elems
  const int conv = (ws_size >= NEED) ? 1 : 0;

  const void *Atxt = txt, *Aimg = img;
  const void *Bqt = Wtq, *Bqi = Wiq, *Bot = Wto, *Boi = Wio;
  if (conv) {
    convert6<<<dim3(864, 6), 256, 0, stream>>>(txt, img, Wtq, Wiq, Wto, Wio,
                                               ws);
    Atxt = ws + 28311552L;
    Aimg = ws + 29097984L;
    Bqt = ws + 35389440L;
    Bqi = ws + 42467328L;
    Bot = ws + 49545216L;
    Boi = ws + 51904512L;
  }

  qkv_gemm<<<dim3(36, 36), 256, 0, stream>>>(Atxt, Aimg, Bqt, Bqi, rope, txt,
                                             conv, qb, kb, vb);
  attn<<<dim3(72, 12), 256, 0, stream>>>(qb, kb, vb, ob);
  out_gemm<<<dim3(12, 36), 256, 0, stream>>>(ob, Bot, Boi, txt, conv, d_out);
}

// Round 4
// 620.341 us; speedup vs baseline: 1.5935x; 1.0773x over previous
//
#include <hip/hip_runtime.h>
#include <hip/hip_bf16.h>
#include <stdint.h>

// JointAttention: B=1, L=512(txt), N=4096(img), HID=1536, H=12, D=128
// Round 6: de-risked attn. The 72KB-static-LDS double-buffered version killed
// the container twice (no diagnostic); only structural discontinuity vs the
// proven R1 kernel was static LDS >64KB. This version: KVBLK=64 single-
// buffered (40KB LDS), 2 barriers/tile (still 2x fewer per key than R1),
// register prefetch of tile kt+1 during tile kt compute, occupancy 3
// blocks/CU (launch_bounds(256,3)), defer-max (T13), exp2-domain softmax
// (SCALE*log2e folded into Q at qkv epilogue), setprio (T5).
// GEMMs unchanged from R3 (verified at 668us total).
// ws (u16 elems): qb[0) kb[7077888) vb[14155776) ob[21233664)
//   txtb[28311552) imgb[29097984) Wqtb[35389440) Wqib[42467328)
//   Wotb[49545216) Woib[51904512) end 54263808 -> 108.5 MB.

typedef __attribute__((ext_vector_type(8))) short short8;
typedef __attribute__((ext_vector_type(4))) float floatx4;

#define DEV __device__ __forceinline__

DEV float bf2f(uint16_t s) {
  union { uint32_t u; float f; } v;
  v.u = (uint32_t)s << 16;
  return v.f;
}
DEV uint16_t f2bf(float f) {
  __hip_bfloat16 h = __float2bfloat16(f);
  return __builtin_bit_cast(uint16_t, h);
}

// Distinguish bf16 vs fp32 buffers (majority vote on exponent sanity).
DEV bool detect_bf16(const void* p) {
  const uint16_t* u = (const uint16_t*)p;
  int sane = 0;
  for (int i = 0; i < 64; ++i) {
    int e = (u[2 * i] >> 7) & 0xFF;
    sane += (e > 90 && e < 145) ? 1 : 0;
  }
  return sane >= 40;
}

DEV short8 load8(const void* base, long idx, bool bf) {
  if (bf) return *(const short8*)((const uint16_t*)base + idx);
  const floatx4* f = (const floatx4*)((const float*)base + idx);
  floatx4 a = f[0], b = f[1];
  short8 r;
  r[0] = (short)f2bf(a[0]); r[1] = (short)f2bf(a[1]);
  r[2] = (short)f2bf(a[2]); r[3] = (short)f2bf(a[3]);
  r[4] = (short)f2bf(b[0]); r[5] = (short)f2bf(b[1]);
  r[6] = (short)f2bf(b[2]); r[7] = (short)f2bf(b[3]);
  return r;
}

DEV float loadElem(const void* base, long idx, bool bf) {
  return bf ? bf2f(((const uint16_t*)base)[idx]) : ((const float*)base)[idx];
}

// ---------------------------------------------------------------------------
// One-time fp32->bf16 (or bf16 copy) of the 6 GEMM operand tensors into ws.
__global__ void convert6(const void* s0, const void* s1, const void* s2,
                         const void* s3, const void* s4, const void* s5,
                         uint16_t* ws) {
  const void* s;
  uint16_t* d;
  long n;
  switch (blockIdx.y) {
    case 0: s = s0; d = ws + 28311552L; n = 786432L; break;   // txt
    case 1: s = s1; d = ws + 29097984L; n = 6291456L; break;  // img
    case 2: s = s2; d = ws + 35389440L; n = 7077888L; break;  // W_txt_qkv
    case 3: s = s3; d = ws + 42467328L; n = 7077888L; break;  // W_img_qkv
    case 4: s = s4; d = ws + 49545216L; n = 2359296L; break;  // W_txt_out
    default: s = s5; d = ws + 51904512L; n = 2359296L; break; // W_img_out
  }
  const bool bf = detect_bf16(s);
  const long stride = (long)gridDim.x * blockDim.x * 8;
  for (long i = ((long)blockIdx.x * blockDim.x + threadIdx.x) * 8; i < n;
       i += stride) {
    if (bf) {
      *(short8*)(d + i) = *(const short8*)((const uint16_t*)s + i);
    } else {
      const floatx4* f = (const floatx4*)((const float*)s + i);
      floatx4 a = f[0], b = f[1];
      short8 r;
      r[0] = (short)f2bf(a[0]); r[1] = (short)f2bf(a[1]);
      r[2] = (short)f2bf(a[2]); r[3] = (short)f2bf(a[3]);
      r[4] = (short)f2bf(b[0]); r[5] = (short)f2bf(b[1]);
      r[6] = (short)f2bf(b[2]); r[7] = (short)f2bf(b[3]);
      *(short8*)(d + i) = r;
    }
  }
}

// ---------------------------------------------------------------------------
// acc[4][4] for C tile (bm,bn) of A[M,K] * B[N,K]^T via bf16 MFMA.
// 128x128 tile, BK=32, register staging + ds_write_b128, XOR chunk swizzle.
DEV void gemm_core(const void* A, const void* B, bool abf, bool bbf, long bm,
                   long bn, int K, uint16_t* sA, uint16_t* sB,
                   floatx4 (&acc)[4][4]) {
  const int t = threadIdx.x;
  const int lane = t & 63, wave = t >> 6, l16 = lane & 15, quad = lane >> 4;
  const int srow = t >> 2, c = t & 3, g = c ^ (srow & 3);
  const int wm = (wave >> 1) * 64, wn = (wave & 1) * 64;
  const int fsl = (quad ^ (l16 & 3)) * 8;
  for (int k0 = 0; k0 < K; k0 += 32) {
    short8 a0 = load8(A, (bm + srow) * (long)K + k0 + g * 8, abf);
    short8 a1 = load8(A, (bm + 64 + srow) * (long)K + k0 + g * 8, abf);
    short8 b0 = load8(B, (bn + srow) * (long)K + k0 + g * 8, bbf);
    short8 b1 = load8(B, (bn + 64 + srow) * (long)K + k0 + g * 8, bbf);
    __syncthreads();  // prev-iter frag reads done before overwrite
    *(short8*)(sA + srow * 32 + c * 8) = a0;
    *(short8*)(sA + (64 + srow) * 32 + c * 8) = a1;
    *(short8*)(sB + srow * 32 + c * 8) = b0;
    *(short8*)(sB + (64 + srow) * 32 + c * 8) = b1;
    __syncthreads();
    short8 af[4], bfr[4];
#pragma unroll
    for (int i = 0; i < 4; ++i) {
      af[i] = *(const short8*)(sA + (wm + i * 16 + l16) * 32 + fsl);
      bfr[i] = *(const short8*)(sB + (wn + i * 16 + l16) * 32 + fsl);
    }
#pragma unroll
    for (int i = 0; i < 4; ++i)
#pragma unroll
      for (int j = 0; j < 4; ++j)
        acc[i][j] = __builtin_amdgcn_mfma_f32_16x16x32_bf16(af[i], bfr[j],
                                                            acc[i][j], 0, 0, 0);
  }
}

// ---------------------------------------------------------------------------
// Merged QKV gemm with fused scatter + rope + q-prescale (SCALE*log2e so attn
// can use exp2 directly). Column tile = one (tensor tt, head h).
__global__ __launch_bounds__(256, 2) void qkv_gemm(
    const void* Atxt, const void* Aimg, const void* Btxt, const void* Bimg,
    const void* rope, const void* det, int conv, uint16_t* qb, uint16_t* kb,
    uint16_t* vb) {
  __shared__ uint16_t sA[128 * 32], sB[128 * 32];
  const bool dbf = detect_bf16(det);      // original input dtype (rope)
  const bool bf = conv ? true : dbf;      // A/B operand dtype
  const int bmb = blockIdx.y;
  const long g0 = (long)bmb * 128;        // global seq row of this block
  const bool is_img = bmb >= 4;           // 4*128 == 512 txt rows
  const void* A = is_img ? Aimg : Atxt;
  const void* B = is_img ? Bimg : Btxt;
  const long bmA = is_img ? g0 - 512 : g0;
  const long bn = (long)blockIdx.x * 128;
  floatx4 acc[4][4] = {};
  gemm_core(A, B, bf, bf, bmA, bn, 1536, sA, sB, acc);

  const int t = threadIdx.x, lane = t & 63, wave = t >> 6;
  const int l16 = lane & 15, quad = lane >> 4;
  const int wm = (wave >> 1) * 64, wn = (wave & 1) * 64;
  const int th = blockIdx.x;
  const int tt = th / 12, h = th - tt * 12;
  uint16_t* dst = tt == 0 ? qb : (tt == 1 ? kb : vb);
  const bool do_rope = is_img && (tt < 2);
#pragma unroll
  for (int i = 0; i < 4; ++i)
#pragma unroll
    for (int j = 0; j < 4; ++j)
#pragma unroll
      for (int r = 0; r < 4; ++r) {
        long g = g0 + wm + i * 16 + quad * 4 + r;  // global seq row
        int d = wn + j * 16 + l16;
        float v = acc[i][j][r];
        float p = __shfl_xor(v, 1);  // partner element of the rope pair
        if (do_rope) {
          int dp = d & ~1;
          long ri = (g - 512) * 128 + dp;
          float cc = loadElem(rope, ri, dbf);
          float ss = loadElem(rope, ri + 1, dbf);
          v = (d & 1) ? (v * cc + p * ss) : (v * cc - p * ss);
        }
        if (tt == 0) v *= 0.12751745f;  // D^-0.5 * log2(e)
        dst[((long)h * 4608 + g) * 128 + d] = f2bf(v);
      }
}

// ---------------------------------------------------------------------------
// Merged out-projection gemm.
__global__ __launch_bounds__(256, 2) void out_gemm(
    const uint16_t* Abf, const void* Btxt, const void* Bimg, const void* det,
    int conv, void* out) {
  __shared__ uint16_t sA[128 * 32], sB[128 * 32];
  const bool dbf = detect_bf16(det);
  const bool bbf = conv ? true : dbf;
  const int bmb = blockIdx.y;
  const long bm = (long)bmb * 128;
  const void* B = bmb >= 4 ? Bimg : Btxt;
  const long bn = (long)blockIdx.x * 128;
  floatx4 acc[4][4] = {};
  gemm_core(Abf, B, true, bbf, bm, bn, 1536, sA, sB, acc);

  const int t = threadIdx.x, lane = t & 63, wave = t >> 6;
  const int l16 = lane & 15, quad = lane >> 4;
  const int wm = (wave >> 1) * 64, wn = (wave & 1) * 64;
#pragma unroll
  for (int i = 0; i < 4; ++i)
#pragma unroll
    for (int j = 0; j < 4; ++j)
#pragma unroll
      for (int r = 0; r < 4; ++r) {
        long row = bm + wm + i * 16 + quad * 4 + r;
        long col = bn + wn + j * 16 + l16;
        long idx = row * 1536 + col;
        if (dbf) ((uint16_t*)out)[idx] = f2bf(acc[i][j][r]);
        else ((float*)out)[idx] = acc[i][j][r];
      }
}

// ---------------------------------------------------------------------------
// Flash attention, KVBLK=64, single-buffered LDS (40KB), register prefetch.
// Block = (64 q-rows, head); 4 waves x 16 q-rows. Two barriers per 64-key
// tile; tile kt+1 global loads issued at top of tile kt (latency hidden under
// compute). Q pre-scaled by SCALE*log2e -> softmax in exp2 domain. Defer-max
// THR=11.5 (log2 units ~ e^8). K rows chunk-swizzled (slot = ch^(row&15));
// V transposed sVt[d][key] chunk-swizzled (ch^(d&7)); P stash per-wave.
__global__ __launch_bounds__(256, 3) void attn(
    const uint16_t* __restrict__ qb, const uint16_t* __restrict__ kb,
    const uint16_t* __restrict__ vb, uint16_t* __restrict__ ob) {
  __shared__ uint16_t sK[64 * 128];    // 16KB
  __shared__ uint16_t sVt[128 * 64];   // 16KB
  __shared__ uint16_t sP[4][16 * 64];  // 8KB

  const int t = threadIdx.x;
  const int lane = t & 63, wave = t >> 6;
  const int l16 = lane & 15, quad = lane >> 4;
  const int h = blockIdx.y;
  const int q0 = blockIdx.x * 64 + wave * 16;

  const uint16_t* Qh = qb + (long)h * 4608 * 128;
  const uint16_t* Kh = kb + (long)h * 4608 * 128;
  const uint16_t* Vh = vb + (long)h * 4608 * 128;

  short8 aq[4];
#pragma unroll
  for (int dk = 0; dk < 4; ++dk)
    aq[dk] = *(const short8*)(Qh + (long)(q0 + l16) * 128 + dk * 32 + quad * 8);

  short8 ones;
#pragma unroll
  for (int j = 0; j < 8; ++j) ones[j] = (short)0x3F80;  // bf16 1.0

  float m_i[4] = {-1e30f, -1e30f, -1e30f, -1e30f};
  floatx4 accL = {};
  floatx4 accO[8] = {};

  const int krow = t >> 2;        // 0..63
  const int kcb = (t & 3) * 4;    // K chunk base (4 chunks of 8 elems)
  const int vk = (t & 31) * 2;    // V key pair
  const int vdb = (t >> 5) * 16;  // V d base (16 d's per thread)

  uint16_t* pw = &sP[wave][0];

  short8 kreg[4], vreg[4];

  auto loadKV = [&](int key0) {
    const uint16_t* kp = Kh + (long)(key0 + krow) * 128 + kcb * 8;
    kreg[0] = *(const short8*)(kp);
    kreg[1] = *(const short8*)(kp + 8);
    kreg[2] = *(const short8*)(kp + 16);
    kreg[3] = *(const short8*)(kp + 24);
    const uint16_t* vp = Vh + (long)(key0 + vk) * 128 + vdb;
    vreg[0] = *(const short8*)(vp);
    vreg[1] = *(const short8*)(vp + 8);
    vreg[2] = *(const short8*)(vp + 128);
    vreg[3] = *(const short8*)(vp + 136);
  };
  auto writeKV = [&]() {
#pragma unroll
    for (int j = 0; j < 4; ++j)
      *(short8*)(sK + krow * 128 + (((kcb + j) ^ (krow & 15)) * 8)) = kreg[j];
    char* vd = (char*)&sVt[0];
#pragma unroll
    for (int hf = 0; hf < 2; ++hf)
#pragma unroll
      for (int j = 0; j < 8; ++j) {
        const int d = vdb + hf * 8 + j;
        uint32_t pk = (uint16_t)vreg[hf][j] |
                      ((uint32_t)(uint16_t)vreg[2 + hf][j] << 16);
        *(uint32_t*)(vd + d * 128 + (((vk >> 3) ^ (d & 7)) * 16) +
                     (vk & 7) * 2) = pk;
      }
  };

  loadKV(0);
  writeKV();
  __syncthreads();

  for (int kt = 0; kt < 72; ++kt) {
    // issue next tile's global loads; they land during this tile's compute
    if (kt < 71) loadKV((kt + 1) * 64);

    // S = Q K^T (already in log2 domain)
    floatx4 sc4[4] = {};
    __builtin_amdgcn_s_setprio(1);
#pragma unroll
    for (int ns = 0; ns < 4; ++ns) {
      const int row = ns * 16 + l16;
#pragma unroll
      for (int dk = 0; dk < 4; ++dk) {
        short8 bk = *(const short8*)(sK + row * 128 +
                                     (((dk * 4 + quad) ^ l16) * 8));
        sc4[ns] = __builtin_amdgcn_mfma_f32_16x16x32_bf16(aq[dk], bk, sc4[ns],
                                                          0, 0, 0);
      }
    }
    __builtin_amdgcn_s_setprio(0);

    // online softmax (log2 domain), defer-max
    float mx[4];
#pragma unroll
    for (int r = 0; r < 4; ++r) {
      float a = fmaxf(fmaxf(sc4[0][r], sc4[1][r]),
                      fmaxf(sc4[2][r], sc4[3][r]));
      a = fmaxf(a, __shfl_xor(a, 1));
      a = fmaxf(a, __shfl_xor(a, 2));
      a = fmaxf(a, __shfl_xor(a, 4));
      a = fmaxf(a, __shfl_xor(a, 8));
      mx[r] = a;
    }
    float ex = fmaxf(fmaxf(mx[0] - m_i[0], mx[1] - m_i[1]),
                     fmaxf(mx[2] - m_i[2], mx[3] - m_i[3]));
    if (!__all(ex <= 11.5f)) {
#pragma unroll
      for (int r = 0; r < 4; ++r) {
        float mn = fmaxf(m_i[r], mx[r]);
        float al = exp2f(m_i[r] - mn);
        m_i[r] = mn;
        accL[r] *= al;
#pragma unroll
        for (int vt = 0; vt < 8; ++vt) accO[vt][r] *= al;
      }
    }
#pragma unroll
    for (int ns = 0; ns < 4; ++ns)
#pragma unroll
      for (int r = 0; r < 4; ++r) sc4[ns][r] = exp2f(sc4[ns][r] - m_i[r]);

    // P -> per-wave stash (C->A transpose), chunk-swizzled (8 chunks/row)
#pragma unroll
    for (int ns = 0; ns < 4; ++ns)
#pragma unroll
      for (int r = 0; r < 4; ++r) {
        const int row = quad * 4 + r;
        const int col = ns * 16 + l16;
        *(uint16_t*)((char*)pw + row * 128 +
                     (((col >> 3) ^ (row & 7)) * 16) + (col & 7) * 2) =
            f2bf(sc4[ns][r]);
      }
    asm volatile("s_waitcnt lgkmcnt(0)" ::: "memory");  // stash drain

    short8 pa[2];
#pragma unroll
    for (int ks = 0; ks < 2; ++ks)
      pa[ks] = *(const short8*)((char*)pw + l16 * 128 +
                                (((ks * 4 + quad) ^ (l16 & 7)) * 16));
    __builtin_amdgcn_s_setprio(1);
    accL = __builtin_amdgcn_mfma_f32_16x16x32_bf16(pa[0], ones, accL, 0, 0, 0);
    accL = __builtin_amdgcn_mfma_f32_16x16x32_bf16(pa[1], ones, accL, 0, 0, 0);
#pragma unroll
    for (int vt = 0; vt < 8; ++vt) {
      const int d = vt * 16 + l16;
#pragma unroll
      for (int ks = 0; ks < 2; ++ks) {
        short8 bv = *(const short8*)((const char*)&sVt[0] + d * 128 +
                                     (((ks * 4 + quad) ^ (d & 7)) * 16));
        accO[vt] = __builtin_amdgcn_mfma_f32_16x16x32_bf16(pa[ks], bv,
                                                           accO[vt], 0, 0, 0);
      }
    }
    __builtin_amdgcn_s_setprio(0);

    __syncthreads();  // all waves done reading sK/sVt
    if (kt < 71) {
      writeKV();      // stage tile kt+1 (waits vmcnt on kreg/vreg here)
      __syncthreads();
    }
  }

#pragma unroll
  for (int r = 0; r < 4; ++r) {
    const long row = q0 + quad * 4 + r;
    const float inv = 1.f / accL[r];
#pragma unroll
    for (int vt = 0; vt < 8; ++vt)
      ob[row * 1536 + h * 128 + vt * 16 + l16] = f2bf(accO[vt][r] * inv);
  }
}

// ---------------------------------------------------------------------------
extern "C" void kernel_launch(void* const* d_in, const int* in_sizes, int n_in,
                              void* d_out, int out_size, void* d_ws,
                              size_t ws_size, hipStream_t stream) {
  const void* txt = d_in[0];
  const void* img = d_in[1];
  const void* rope = d_in[2];
  const void* Wtq = d_in[3];
  const void* Wiq = d_in[4];
  const void* Wto = d_in[5];
  const void* Wio = d_in[6];

  uint16_t* ws = (uint16_t*)d_ws;
  uint16_t* qb = ws;                  // [12][4608][128]
  uint16_t* kb = ws + 7077888L;
  uint16_t* vb = ws + 14155776L;
  uint16_t* ob = ws + 21233664L;      // [4608][1536]

  const size_t NEED = 108527616ULL;   // 54,263,808 u16 elems
  const int conv = (ws_size >= NEED) ? 1 : 0;

  const void *Atxt = txt, *Aimg = img;
  const void *Bqt = Wtq, *Bqi = Wiq, *Bot = Wto, *Boi = Wio;
  if (conv) {
    convert6<<<dim3(864, 6), 256, 0, stream>>>(txt, img, Wtq, Wiq, Wto, Wio,
                                               ws);
    Atxt = ws + 28311552L;
    Aimg = ws + 29097984L;
    Bqt = ws + 35389440L;
    Bqi = ws + 42467328L;
    Bot = ws + 49545216L;
    Boi = ws + 51904512L;
  }

  qkv_gemm<<<dim3(36, 36), 256, 0, stream>>>(Atxt, Aimg, Bqt, Bqi, rope, txt,
                                             conv, qb, kb, vb);
  attn<<<dim3(72, 12), 256, 0, stream>>>(qb, kb, vb, ob);
  out_gemm<<<dim3(12, 36), 256, 0, stream>>>(ob, Bot, Boi, txt, conv, d_out);
}